// Round 15
// baseline (1000.520 us; speedup 1.0000x reference)
//
#include <hip/hip_runtime.h>
#include <hip/hip_bf16.h>
#include <math.h>

// Problem constants
#define BB 16
#define QQ 100
#define NH 8
#define HWN 4096
#define NORM_FACT 0.17677669529663687f   // 32^-0.5
#define QPAD 112        // q rows padded to 112 (7 tiles of 16)

typedef short bf16x8_t __attribute__((ext_vector_type(8)));
typedef float f32x4_t  __attribute__((ext_vector_type(4)));

__device__ __forceinline__ unsigned short bf16bits(float f) {
    __hip_bfloat16 h = __float2bfloat16(f);           // RNE
    return __builtin_bit_cast(unsigned short, h);
}
__device__ __forceinline__ float bf16tof(unsigned short u) {
    union { unsigned int i; float f; } x; x.i = (unsigned int)u << 16; return x.f;
}

// ---------------- K0: WqT (fp32 transpose) + Wk -> bf16 -----------------------
__global__ void k_prep(const float* __restrict__ Wq, const float* __restrict__ Wk,
                       float* __restrict__ WqT, unsigned short* __restrict__ Wkbf) {
    int idx = blockIdx.x;
    int h = threadIdx.x;
    if (idx < 256) {
        WqT[idx * 256 + h] = Wq[h * 256 + idx];
    } else {
        int r = idx - 256;
        Wkbf[r * 256 + h] = bf16bits(Wk[r * 256 + h]);
    }
}

// ---------------- K1: q-proj (DIAGNOSTIC: reps) --------------------------------
__global__ __launch_bounds__(256) void k_qproj(const float* __restrict__ q,
                                               const float* __restrict__ WqT,
                                               const float* __restrict__ bq,
                                               unsigned short* __restrict__ qphi,
                                               unsigned short* __restrict__ qplo,
                                               int reps) {
    int blk = blockIdx.x;             // 16 b x 28 tiles of 4 rows
    int b = blk / 28, q0 = (blk % 28) * 4;
    int h = threadIdx.x;
    size_t obase = ((size_t)b * QPAD + q0) * 256 + h;
    if (q0 >= QQ) {                   // padding rows -> zeros
#pragma unroll
        for (int i = 0; i < 4; ++i) { qphi[obase + i * 256] = 0; qplo[obase + i * 256] = 0; }
        return;
    }
    __shared__ float qsh[4][256];
    int ibase = (b * QQ + q0) * 256;
#pragma unroll
    for (int i = 0; i < 4; ++i) qsh[i][h] = q[ibase + i * 256 + h];
    __syncthreads();
#pragma unroll 1
    for (int rep = 0; rep < reps; ++rep) {
        int off0 = 0; asm volatile("" : "+v"(off0));   // opaque 0: defeat hoisting
        float bias = bq[h];
        float a0 = bias, a1 = bias, a2 = bias, a3 = bias;
        for (int c = 0; c < 256; ++c) {
            float wv = WqT[c * 256 + h + off0];
            a0 = fmaf(qsh[0][c], wv, a0);
            a1 = fmaf(qsh[1][c], wv, a1);
            a2 = fmaf(qsh[2][c], wv, a2);
            a3 = fmaf(qsh[3][c], wv, a3);
        }
        float a[4] = {a0 * NORM_FACT, a1 * NORM_FACT, a2 * NORM_FACT, a3 * NORM_FACT};
#pragma unroll
        for (int i = 0; i < 4; ++i) {
            unsigned short hi = bf16bits(a[i]);
            qphi[obase + i * 256] = hi;
            qplo[obase + i * 256] = bf16bits(a[i] - bf16tof(hi));
        }
    }
}

// ---------------- K2: fused transpose+kproj (DIAGNOSTIC: reps) -----------------
__global__ __launch_bounds__(512) void k_kproj3(const float* __restrict__ k,
                                                const unsigned short* __restrict__ Wkbf,
                                                const float* __restrict__ bk,
                                                unsigned short* __restrict__ kpT,
                                                int reps) {
    int b = blockIdx.y;
    int hwblk = blockIdx.x * 64;
    int t = threadIdx.x;
    int w = t >> 6, lane = t & 63;
    int hwt = w & 3, oh = w >> 2;
    int n15 = lane & 15, kg = lane >> 4;
    int hw_l = hwt * 16 + n15;

    __shared__ float lds_f[64][140];
#pragma unroll 1
    for (int rep = 0; rep < reps; ++rep) {
        int off0 = 0; asm volatile("" : "+v"(off0));
        __syncthreads();

        f32x4_t acc[8];
#pragma unroll
        for (int m = 0; m < 8; ++m) acc[m] = f32x4_t{0.f, 0.f, 0.f, 0.f};

        const float* kb = k + (size_t)b * 256 * HWN + hwblk + off0;
        const unsigned short* wbase = Wkbf + ((size_t)(oh * 128 + n15)) * 256 + kg * 8;
        int c_l = t >> 4, l16 = t & 15;

#pragma unroll
        for (int chunk = 0; chunk < 2; ++chunk) {
#pragma unroll
            for (int p = 0; p < 4; ++p) {
                int cc = p * 32 + c_l;
                float4 v = *(const float4*)(kb + (size_t)(chunk * 128 + cc) * HWN + l16 * 4);
                lds_f[l16 * 4 + 0][cc] = v.x;
                lds_f[l16 * 4 + 1][cc] = v.y;
                lds_f[l16 * 4 + 2][cc] = v.z;
                lds_f[l16 * 4 + 3][cc] = v.w;
            }
            __syncthreads();
#pragma unroll
            for (int ksl = 0; ksl < 4; ++ksl) {
                f32x4_t f0 = *(const f32x4_t*)&lds_f[hw_l][ksl * 32 + kg * 8];
                f32x4_t f1 = *(const f32x4_t*)&lds_f[hw_l][ksl * 32 + kg * 8 + 4];
                bf16x8_t bfrag;
#pragma unroll
                for (int j = 0; j < 4; ++j) {
                    bfrag[j]     = (short)bf16bits(f0[j]);
                    bfrag[4 + j] = (short)bf16bits(f1[j]);
                }
                int ks = chunk * 4 + ksl;
#pragma unroll
                for (int m = 0; m < 8; ++m) {
                    bf16x8_t afrag = *reinterpret_cast<const bf16x8_t*>(wbase + (size_t)m * 16 * 256 + ks * 32);
                    acc[m] = __builtin_amdgcn_mfma_f32_16x16x32_bf16(afrag, bfrag, acc[m], 0, 0, 0);
                }
            }
            __syncthreads();
        }

        unsigned short* tile2 = (unsigned short*)lds_f;
#pragma unroll
        for (int m = 0; m < 8; ++m) {
            ushort4 pk;
            unsigned short* pkp = (unsigned short*)&pk;
#pragma unroll
            for (int r = 0; r < 4; ++r) {
                int o = oh * 128 + m * 16 + kg * 4 + r;
                pkp[r] = bf16bits(acc[m][r] + bk[o]);
            }
            *(ushort4*)&tile2[(size_t)hw_l * 264 + oh * 128 + m * 16 + kg * 4] = pk;
        }
        __syncthreads();
        int l5 = t & 31;
#pragma unroll
        for (int it = 0; it < 4; ++it) {
            int row = it * 16 + (t >> 5);
            uint4 v = *(const uint4*)&tile2[(size_t)row * 264 + l5 * 8];
            *(uint4*)(kpT + ((size_t)b * HWN + hwblk + row) * 256 + l5 * 8 + off0) = v;
        }
    }
}

// ---------------- K3: sum-pass (DIAGNOSTIC: reps) ------------------------------
__global__ __launch_bounds__(256) void k_sums(const unsigned short* __restrict__ qphi,
                                              const unsigned short* __restrict__ qplo,
                                              const unsigned short* __restrict__ kpT,
                                              const int* __restrict__ mask,
                                              float* __restrict__ partial,
                                              int reps) {
    int hwb = blockIdx.x, b = blockIdx.y;
    int t = threadIdx.x, w = t >> 6, lane = t & 63;
    int n15 = lane & 15, kg = lane >> 4;
    int hw = hwb * 64 + w * 16 + n15;
    float mm = mask[b * HWN + hw] ? 0.0f : 1.0f;

    __shared__ float ldsbuf[8960];
    unsigned short* sA = (unsigned short*)ldsbuf;

#pragma unroll 1
    for (int rep = 0; rep < reps; ++rep) {
        int off0 = 0; asm volatile("" : "+v"(off0));
        __syncthreads();   // prior rep's reduce reads done before restage

        const unsigned short* brow = kpT + ((size_t)(b * HWN + hw)) * 256 + kg * 8 + off0;
        bf16x8_t bfr[8];
#pragma unroll
        for (int n = 0; n < NH; ++n)
            bfr[n] = *reinterpret_cast<const bf16x8_t*>(brow + n * 32);

        const unsigned short* ghi = qphi + (size_t)b * QPAD * 256 + off0;
        const unsigned short* glo = qplo + (size_t)b * QPAD * 256 + off0;
        int srow = t >> 4, schunk = t & 15;

        float sums[7][4] = {};
#pragma unroll 1
        for (int mt = 0; mt < 7; ++mt) {
            const unsigned short* shi = ghi + (size_t)(mt * 16 + srow) * 256 + schunk * 16;
            const unsigned short* slo = glo + (size_t)(mt * 16 + srow) * 256 + schunk * 16;
            uint4 vhi0 = *(const uint4*)(shi);
            uint4 vhi1 = *(const uint4*)(shi + 8);
            uint4 vlo0 = *(const uint4*)(slo);
            uint4 vlo1 = *(const uint4*)(slo + 8);
            *(uint4*)&sA[srow * 264 + schunk * 16]          = vhi0;
            *(uint4*)&sA[srow * 264 + schunk * 16 + 8]      = vhi1;
            *(uint4*)&sA[16 * 264 + srow * 264 + schunk * 16]     = vlo0;
            *(uint4*)&sA[16 * 264 + srow * 264 + schunk * 16 + 8] = vlo1;
            __syncthreads();
#pragma unroll
            for (int n = 0; n < NH; ++n) {
                bf16x8_t ahi = *reinterpret_cast<const bf16x8_t*>(&sA[n15 * 264 + n * 32 + kg * 8]);
                bf16x8_t alo = *reinterpret_cast<const bf16x8_t*>(&sA[16 * 264 + n15 * 264 + n * 32 + kg * 8]);
                f32x4_t a2 = {0.f, 0.f, 0.f, 0.f};
                a2 = __builtin_amdgcn_mfma_f32_16x16x32_bf16(ahi, bfr[n], a2, 0, 0, 0);
                a2 = __builtin_amdgcn_mfma_f32_16x16x32_bf16(alo, bfr[n], a2, 0, 0, 0);
#pragma unroll
                for (int r = 0; r < 4; ++r)
                    sums[mt][r] += __expf(a2[r]) * mm;
            }
            __syncthreads();
        }

        float* R = ldsbuf + w * 112 * 20;
#pragma unroll
        for (int mt = 0; mt < 7; ++mt)
#pragma unroll
            for (int r = 0; r < 4; ++r)
                R[(mt * 16 + kg * 4 + r) * 20 + n15] = sums[mt][r];
        if (lane < 56) {
#pragma unroll
            for (int p = 0; p < 2; ++p) {
                int row = lane + p * 56;
                f32x4_t v0 = *(const f32x4_t*)&R[row * 20 + 0];
                f32x4_t v1 = *(const f32x4_t*)&R[row * 20 + 4];
                f32x4_t v2 = *(const f32x4_t*)&R[row * 20 + 8];
                f32x4_t v3 = *(const f32x4_t*)&R[row * 20 + 12];
                float s = (v0[0]+v0[1]+v0[2]+v0[3]) + (v1[0]+v1[1]+v1[2]+v1[3])
                        + (v2[0]+v2[1]+v2[2]+v2[3]) + (v3[0]+v3[1]+v3[2]+v3[3]);
                partial[((size_t)b * QPAD + row) * 256 + hwb * 4 + w] = s;
            }
        }
    }
}

// ---------------- K4: inv_sum[b,q] ---------------------------------------------
__global__ __launch_bounds__(256) void k_invsum(const float* __restrict__ partial,
                                                float* __restrict__ inv) {
    int blk = blockIdx.x;            // 0..1599
    int b = blk / QQ, qq = blk % QQ;
    const float* p = partial + ((size_t)b * QPAD + qq) * 256;
    int t = threadIdx.x;
    float v = p[t];
#pragma unroll
    for (int off = 32; off; off >>= 1) v += __shfl_xor(v, off, 64);
    __shared__ float red[4];
    if ((t & 63) == 0) red[t >> 6] = v;
    __syncthreads();
    if (t == 0) inv[blk] = 1.0f / (red[0] + red[1] + red[2] + red[3]);
}

// ---------------- K5: write-pass (DIAGNOSTIC: reps) ----------------------------
__global__ __launch_bounds__(256) void k_write(const unsigned short* __restrict__ qphi,
                                               const unsigned short* __restrict__ qplo,
                                               const unsigned short* __restrict__ kpT,
                                               const int* __restrict__ mask,
                                               const float* __restrict__ inv,
                                               float* __restrict__ out,
                                               int reps) {
    int qt = blockIdx.x, n = blockIdx.y, b = blockIdx.z;
    int t = threadIdx.x, w = t >> 6, lane = t & 63;
    int n15 = lane & 15, kg = lane >> 4;

    bf16x8_t ahi = *reinterpret_cast<const bf16x8_t*>(
        qphi + ((size_t)(b * QPAD + qt * 16 + n15)) * 256 + n * 32 + kg * 8);
    bf16x8_t alo = *reinterpret_cast<const bf16x8_t*>(
        qplo + ((size_t)(b * QPAD + qt * 16 + n15)) * 256 + n * 32 + kg * 8);
    float invq[4];
#pragma unroll
    for (int r = 0; r < 4; ++r) {
        int qrow = qt * 16 + kg * 4 + r;
        invq[r] = (qrow < QQ) ? inv[b * QQ + qrow] : 0.0f;
    }

    __shared__ float lt[16][260];

#pragma unroll 1
    for (int rep = 0; rep < reps; ++rep) {
        int off0 = 0; asm volatile("" : "+v"(off0));
        bf16x8_t bc[4], bn[4];
        float mc[4], mn[4];
#pragma unroll
        for (int ht = 0; ht < 4; ++ht) {
            int hw = w * 64 + ht * 16 + n15;
            bc[ht] = *reinterpret_cast<const bf16x8_t*>(
                kpT + ((size_t)(b * HWN + hw)) * 256 + n * 32 + kg * 8 + off0);
            mc[ht] = mask[b * HWN + hw + off0] ? 0.0f : 1.0f;
            bn[ht] = bc[ht];
            mn[ht] = mc[ht];
        }
        __syncthreads();   // lt free from previous rep

#pragma unroll 1
        for (int hws = 0; hws < 16; ++hws) {
            if (hws < 15) {
#pragma unroll
                for (int ht = 0; ht < 4; ++ht) {
                    int hw = (hws + 1) * 256 + w * 64 + ht * 16 + n15;
                    bn[ht] = *reinterpret_cast<const bf16x8_t*>(
                        kpT + ((size_t)(b * HWN + hw)) * 256 + n * 32 + kg * 8 + off0);
                    mn[ht] = mask[b * HWN + hw + off0] ? 0.0f : 1.0f;
                }
            }
#pragma unroll
            for (int ht = 0; ht < 4; ++ht) {
                f32x4_t acc = {0.f, 0.f, 0.f, 0.f};
                acc = __builtin_amdgcn_mfma_f32_16x16x32_bf16(ahi, bc[ht], acc, 0, 0, 0);
                acc = __builtin_amdgcn_mfma_f32_16x16x32_bf16(alo, bc[ht], acc, 0, 0, 0);
#pragma unroll
                for (int r = 0; r < 4; ++r)
                    lt[kg * 4 + r][w * 64 + ht * 16 + n15] = __expf(acc[r]) * mc[ht] * invq[r];
            }
            __syncthreads();
#pragma unroll
            for (int j = 0; j < 4; ++j) {
                int row = w * 4 + j;
                int qrow = qt * 16 + row;
                f32x4_t v4 = *(const f32x4_t*)&lt[row][lane * 4];
                if (qrow < QQ)
                    __builtin_nontemporal_store(v4,
                        (f32x4_t*)(out + (((size_t)(b * QQ + qrow)) * NH + n) * HWN + hws * 256 + lane * 4));
            }
            __syncthreads();
#pragma unroll
            for (int ht = 0; ht < 4; ++ht) { bc[ht] = bn[ht]; mc[ht] = mn[ht]; }
        }
    }
}

extern "C" void kernel_launch(void* const* d_in, const int* in_sizes, int n_in,
                              void* d_out, int out_size, void* d_ws, size_t ws_size,
                              hipStream_t stream) {
    const float* q    = (const float*)d_in[0];
    const float* k    = (const float*)d_in[1];
    const float* Wq   = (const float*)d_in[2];
    const float* bq   = (const float*)d_in[3];
    const float* Wk   = (const float*)d_in[4];
    const float* bk   = (const float*)d_in[5];
    const int*   mask = (const int*)d_in[6];
    float* out = (float*)d_out;

    char* base = (char*)d_ws;
    unsigned short* kpT  = (unsigned short*)(base);              // 33,554,432 B
    unsigned short* qphi = (unsigned short*)(base + 33554432);   //    917,504 B
    unsigned short* qplo = (unsigned short*)(base + 34471936);   //    917,504 B
    float*  WqT     = (float*)(base + 35389440);                 //    262,144 B
    unsigned short* Wkbf = (unsigned short*)(base + 35651584);   //    131,072 B
    float*  partial = (float*)(base + 35782656);                 //  1,835,008 B
    float*  inv     = (float*)(base + 37617664);                 //      6,400 B
    if (ws_size < (size_t)37624064) return;

    k_prep  <<<dim3(512), dim3(256), 0, stream>>>(Wq, Wk, WqT, Wkbf);
    k_qproj <<<dim3(448), dim3(256), 0, stream>>>(q, WqT, bq, qphi, qplo, 20);
    k_kproj3<<<dim3(64, 16), dim3(512), 0, stream>>>(k, Wkbf, bk, kpT, 8);
    k_sums  <<<dim3(64, 16), dim3(256), 0, stream>>>(qphi, qplo, kpT, mask, partial, 6);
    k_invsum<<<dim3(1600), dim3(256), 0, stream>>>(partial, inv);
    k_write <<<dim3(7, 8, 16), dim3(256), 0, stream>>>(qphi, qplo, kpT, mask, inv, out, 2);
}

// Round 16
// 186.516 us; speedup vs baseline: 5.3642x; 5.3642x over previous
//
#include <hip/hip_runtime.h>
#include <hip/hip_bf16.h>
#include <math.h>

// Problem constants
#define BB 16
#define QQ 100
#define NH 8
#define HWN 4096
#define NORM_FACT 0.17677669529663687f   // 32^-0.5
#define QPAD 112        // q rows padded to 112 (7 tiles of 16)

// kpf fragment-major layout: [b][tile(256)][n(8)][kg(4)][n15(16)][8 shorts]
// element (b, hw, o): tile=hw>>4, n15=hw&15, n=o>>5, kg=(o>>3)&3, j=o&7
#define KPF_IDX(b, tile, n, kg) (((((size_t)(b) * 256 + (tile)) * 8 + (n)) * 4 + (kg)) * 128)

typedef short bf16x8_t __attribute__((ext_vector_type(8)));
typedef float f32x4_t  __attribute__((ext_vector_type(4)));

__device__ __forceinline__ unsigned short bf16bits(float f) {
    __hip_bfloat16 h = __float2bfloat16(f);           // RNE
    return __builtin_bit_cast(unsigned short, h);
}
__device__ __forceinline__ float bf16tof(unsigned short u) {
    union { unsigned int i; float f; } x; x.i = (unsigned int)u << 16; return x.f;
}

// ---------------- K0: WqT (fp32 transpose) + Wk -> bf16 -----------------------
__global__ void k_prep(const float* __restrict__ Wq, const float* __restrict__ Wk,
                       float* __restrict__ WqT, unsigned short* __restrict__ Wkbf) {
    int idx = blockIdx.x;
    int h = threadIdx.x;
    if (idx < 256) {
        WqT[idx * 256 + h] = Wq[h * 256 + idx];
    } else {
        int r = idx - 256;
        Wkbf[r * 256 + h] = bf16bits(Wk[r * 256 + h]);
    }
}

// ---------------- K1: q-proj -> bf16 hi/lo split, padded to 112 rows ----------
__global__ __launch_bounds__(256) void k_qproj(const float* __restrict__ q,
                                               const float* __restrict__ WqT,
                                               const float* __restrict__ bq,
                                               unsigned short* __restrict__ qphi,
                                               unsigned short* __restrict__ qplo) {
    int blk = blockIdx.x;             // 16 b x 28 tiles of 4 rows
    int b = blk / 28, q0 = (blk % 28) * 4;
    int h = threadIdx.x;
    size_t obase = ((size_t)b * QPAD + q0) * 256 + h;
    if (q0 >= QQ) {                   // padding rows -> zeros
#pragma unroll
        for (int i = 0; i < 4; ++i) { qphi[obase + i * 256] = 0; qplo[obase + i * 256] = 0; }
        return;
    }
    __shared__ float qsh[4][256];
    int ibase = (b * QQ + q0) * 256;
#pragma unroll
    for (int i = 0; i < 4; ++i) qsh[i][h] = q[ibase + i * 256 + h];
    __syncthreads();
    float bias = bq[h];
    float a0 = bias, a1 = bias, a2 = bias, a3 = bias;
    for (int c = 0; c < 256; ++c) {
        float wv = WqT[c * 256 + h];
        a0 = fmaf(qsh[0][c], wv, a0);
        a1 = fmaf(qsh[1][c], wv, a1);
        a2 = fmaf(qsh[2][c], wv, a2);
        a3 = fmaf(qsh[3][c], wv, a3);
    }
    float a[4] = {a0 * NORM_FACT, a1 * NORM_FACT, a2 * NORM_FACT, a3 * NORM_FACT};
#pragma unroll
    for (int i = 0; i < 4; ++i) {
        unsigned short hi = bf16bits(a[i]);
        qphi[obase + i * 256] = hi;
        qplo[obase + i * 256] = bf16bits(a[i] - bf16tof(hi));
    }
}

// ---------------- K2: fused transpose+kproj -> kpf fragment-major -------------
// grid (64 hwblk-of-64, 16 b), 512 threads (8 waves): wave = (hwt 16hw, oh 128o)
// LDS 17.4 KB: fp32 staging [64][68] x 4 chunks of 64c; reused as [64][132]
// bf16 half-tile in a 2-pass epilogue. Output kpf: consumers load 1KB contiguous.
__global__ __launch_bounds__(512) void k_kproj4(const float* __restrict__ k,
                                                const unsigned short* __restrict__ Wkbf,
                                                const float* __restrict__ bk,
                                                unsigned short* __restrict__ kpf) {
    int b = blockIdx.y;
    int hwblk = blockIdx.x * 64;
    int t = threadIdx.x;
    int w = t >> 6, lane = t & 63;
    int hwt = w & 3, oh = w >> 2;          // wave -> (16-hw tile, 128-o half)
    int n15 = lane & 15, kg = lane >> 4;
    int hw_l = hwt * 16 + n15;

    __shared__ float lds_f[64][68];        // 17,408 B (also reused as tile2)

    f32x4_t acc[8];
#pragma unroll
    for (int m = 0; m < 8; ++m) acc[m] = f32x4_t{0.f, 0.f, 0.f, 0.f};

    const float* kb = k + (size_t)b * 256 * HWN + hwblk;
    const unsigned short* wbase = Wkbf + ((size_t)(oh * 128 + n15)) * 256 + kg * 8;
    int c_l = t >> 4, l16 = t & 15;        // staging: 32 c-rows x 16 lanes (256B rows)

#pragma unroll 1
    for (int chunk = 0; chunk < 4; ++chunk) {
        // stage [64 c][64 hw] fp32 chunk: 2 float4 per thread, 256B segments
#pragma unroll
        for (int p = 0; p < 2; ++p) {
            int cc = p * 32 + c_l;                     // 0..63 within chunk
            float4 v = *(const float4*)(kb + (size_t)(chunk * 64 + cc) * HWN + l16 * 4);
            lds_f[l16 * 4 + 0][cc] = v.x;
            lds_f[l16 * 4 + 1][cc] = v.y;
            lds_f[l16 * 4 + 2][cc] = v.z;
            lds_f[l16 * 4 + 3][cc] = v.w;
        }
        __syncthreads();
#pragma unroll
        for (int ksl = 0; ksl < 2; ++ksl) {
            f32x4_t f0 = *(const f32x4_t*)&lds_f[hw_l][ksl * 32 + kg * 8];
            f32x4_t f1 = *(const f32x4_t*)&lds_f[hw_l][ksl * 32 + kg * 8 + 4];
            bf16x8_t bfrag;
#pragma unroll
            for (int j = 0; j < 4; ++j) {
                bfrag[j]     = (short)bf16bits(f0[j]);
                bfrag[4 + j] = (short)bf16bits(f1[j]);
            }
            int ks = chunk * 2 + ksl;
#pragma unroll
            for (int m = 0; m < 8; ++m) {
                bf16x8_t afrag = *reinterpret_cast<const bf16x8_t*>(wbase + (size_t)m * 16 * 256 + ks * 32);
                acc[m] = __builtin_amdgcn_mfma_f32_16x16x32_bf16(afrag, bfrag, acc[m], 0, 0, 0);
            }
        }
        __syncthreads();
    }

    // epilogue: two o-half passes through tile2 [64 hw][132 o-half] bf16
    unsigned short* tile2 = (unsigned short*)lds_f;    // 16,896 B < 17,408 B
#pragma unroll 1
    for (int ohp = 0; ohp < 2; ++ohp) {
        if (oh == ohp) {
#pragma unroll
            for (int m = 0; m < 8; ++m) {
                ushort4 pk;
                unsigned short* pkp = (unsigned short*)&pk;
#pragma unroll
                for (int r = 0; r < 4; ++r) {
                    int o = ohp * 128 + m * 16 + kg * 4 + r;
                    pkp[r] = bf16bits(acc[m][r] + bk[o]);
                }
                *(ushort4*)&tile2[(size_t)hw_l * 132 + m * 16 + kg * 4] = pk;
            }
        }
        __syncthreads();
        // copy half-tile to kpf fragment-major: each thread 2x uint4 contiguous
        {
            int s = t * 2;                 // frag-lane slot pair
            int tile = s >> 8;             // 0..3 local 16-hw tile
            int n2   = (s >> 6) & 3;       // head within half
            int kgc  = (s >> 4) & 3;
            int nl   = s & 15;             // n15 (even), covers nl and nl+1
            const unsigned short* src = &tile2[(size_t)(tile * 16 + nl) * 132 + n2 * 32 + kgc * 8];
            uint4 v0 = *(const uint4*)(src);
            uint4 v1 = *(const uint4*)(src + 132);
            size_t dst = KPF_IDX(b, blockIdx.x * 4 + tile, ohp * 4 + n2, kgc) + nl * 8;
            *(uint4*)(kpf + dst)     = v0;
            *(uint4*)(kpf + dst + 8) = v1;
        }
        __syncthreads();
    }
}

// ---------------- K3: sum-pass — LDS-staged q, contiguous kpf B-frags ----------
// grid (64 hwb of 64, 16 b); 4 waves; wave = one 16-hw tile, all heads/q.
__global__ __launch_bounds__(256) void k_sums(const unsigned short* __restrict__ qphi,
                                              const unsigned short* __restrict__ qplo,
                                              const unsigned short* __restrict__ kpf,
                                              const int* __restrict__ mask,
                                              float* __restrict__ partial) {
    int hwb = blockIdx.x, b = blockIdx.y;
    int t = threadIdx.x, w = t >> 6, lane = t & 63;
    int n15 = lane & 15, kg = lane >> 4;
    int hw = hwb * 64 + w * 16 + n15;
    float mm = mask[b * HWN + hw] ? 0.0f : 1.0f;

    __shared__ float ldsbuf[8960];                 // 35,840 B (stage + reduce overlay)
    unsigned short* sA = (unsigned short*)ldsbuf;  // stage: qphi[16][264] | qplo[16][264]

    // preload all 8 B-frags: contiguous 1KB per wave instruction
    int tg = hwb * 4 + w;
    bf16x8_t bfr[8];
#pragma unroll
    for (int n = 0; n < NH; ++n)
        bfr[n] = *reinterpret_cast<const bf16x8_t*>(kpf + KPF_IDX(b, tg, n, kg) + n15 * 8);

    const unsigned short* ghi = qphi + (size_t)b * QPAD * 256;
    const unsigned short* glo = qplo + (size_t)b * QPAD * 256;
    int srow = t >> 4, schunk = t & 15;            // stage role: row 0..15, 32B chunk

    float sums[7][4] = {};
#pragma unroll 1
    for (int mt = 0; mt < 7; ++mt) {
        const unsigned short* shi = ghi + (size_t)(mt * 16 + srow) * 256 + schunk * 16;
        const unsigned short* slo = glo + (size_t)(mt * 16 + srow) * 256 + schunk * 16;
        uint4 vhi0 = *(const uint4*)(shi);
        uint4 vhi1 = *(const uint4*)(shi + 8);
        uint4 vlo0 = *(const uint4*)(slo);
        uint4 vlo1 = *(const uint4*)(slo + 8);
        *(uint4*)&sA[srow * 264 + schunk * 16]          = vhi0;
        *(uint4*)&sA[srow * 264 + schunk * 16 + 8]      = vhi1;
        *(uint4*)&sA[16 * 264 + srow * 264 + schunk * 16]     = vlo0;
        *(uint4*)&sA[16 * 264 + srow * 264 + schunk * 16 + 8] = vlo1;
        __syncthreads();
#pragma unroll
        for (int n = 0; n < NH; ++n) {
            bf16x8_t ahi = *reinterpret_cast<const bf16x8_t*>(&sA[n15 * 264 + n * 32 + kg * 8]);
            bf16x8_t alo = *reinterpret_cast<const bf16x8_t*>(&sA[16 * 264 + n15 * 264 + n * 32 + kg * 8]);
            f32x4_t a2 = {0.f, 0.f, 0.f, 0.f};
            a2 = __builtin_amdgcn_mfma_f32_16x16x32_bf16(ahi, bfr[n], a2, 0, 0, 0);
            a2 = __builtin_amdgcn_mfma_f32_16x16x32_bf16(alo, bfr[n], a2, 0, 0, 0);
#pragma unroll
            for (int r = 0; r < 4; ++r)
                sums[mt][r] += __expf(a2[r]) * mm;
        }
        __syncthreads();
    }

    // per-wave LDS reduce: region [w][112 rows][20] floats (overlays stage buffer)
    float* R = ldsbuf + w * 112 * 20;
#pragma unroll
    for (int mt = 0; mt < 7; ++mt)
#pragma unroll
        for (int r = 0; r < 4; ++r)
            R[(mt * 16 + kg * 4 + r) * 20 + n15] = sums[mt][r];
    if (lane < 56) {
#pragma unroll
        for (int p = 0; p < 2; ++p) {
            int row = lane + p * 56;
            f32x4_t v0 = *(const f32x4_t*)&R[row * 20 + 0];
            f32x4_t v1 = *(const f32x4_t*)&R[row * 20 + 4];
            f32x4_t v2 = *(const f32x4_t*)&R[row * 20 + 8];
            f32x4_t v3 = *(const f32x4_t*)&R[row * 20 + 12];
            float s = (v0[0]+v0[1]+v0[2]+v0[3]) + (v1[0]+v1[1]+v1[2]+v1[3])
                    + (v2[0]+v2[1]+v2[2]+v2[3]) + (v3[0]+v3[1]+v3[2]+v3[3]);
            partial[((size_t)b * QPAD + row) * 256 + hwb * 4 + w] = s;
        }
    }
}

// ---------------- K4: inv_sum[b,q] — one block per (b,q), 256-slot reduce -----
__global__ __launch_bounds__(256) void k_invsum(const float* __restrict__ partial,
                                                float* __restrict__ inv) {
    int blk = blockIdx.x;            // 0..1599
    int b = blk / QQ, qq = blk % QQ;
    const float* p = partial + ((size_t)b * QPAD + qq) * 256;
    int t = threadIdx.x;
    float v = p[t];
#pragma unroll
    for (int off = 32; off; off >>= 1) v += __shfl_xor(v, off, 64);
    __shared__ float red[4];
    if ((t & 63) == 0) red[t >> 6] = v;
    __syncthreads();
    if (t == 0) inv[blk] = 1.0f / (red[0] + red[1] + red[2] + red[3]);
}

// ---------------- K5: write-pass — contiguous kpf loads, 16KB row streams -----
// grid (7 qt, 8 n, 16 b); 4 waves; block owns 16 q rows x full 4096 hw for one n.
__global__ __launch_bounds__(256) void k_write(const unsigned short* __restrict__ qphi,
                                               const unsigned short* __restrict__ qplo,
                                               const unsigned short* __restrict__ kpf,
                                               const int* __restrict__ mask,
                                               const float* __restrict__ inv,
                                               float* __restrict__ out) {
    int qt = blockIdx.x, n = blockIdx.y, b = blockIdx.z;
    int t = threadIdx.x, w = t >> 6, lane = t & 63;
    int n15 = lane & 15, kg = lane >> 4;

    // per-block constants: A-frags + inv (loaded once)
    bf16x8_t ahi = *reinterpret_cast<const bf16x8_t*>(
        qphi + ((size_t)(b * QPAD + qt * 16 + n15)) * 256 + n * 32 + kg * 8);
    bf16x8_t alo = *reinterpret_cast<const bf16x8_t*>(
        qplo + ((size_t)(b * QPAD + qt * 16 + n15)) * 256 + n * 32 + kg * 8);
    float invq[4];
#pragma unroll
    for (int r = 0; r < 4; ++r) {
        int qrow = qt * 16 + kg * 4 + r;
        invq[r] = (qrow < QQ) ? inv[b * QQ + qrow] : 0.0f;
    }

    __shared__ float lt[16][260];     // block staging: 16q x 256hw (16.6 KB)

    // software pipeline: preload hws=0 B-frags + mask (contiguous kpf loads)
    bf16x8_t bc[4], bn[4];
    float mc[4], mn[4];
#pragma unroll
    for (int ht = 0; ht < 4; ++ht) {
        int tg = w * 4 + ht;
        bc[ht] = *reinterpret_cast<const bf16x8_t*>(kpf + KPF_IDX(b, tg, n, kg) + n15 * 8);
        mc[ht] = mask[b * HWN + w * 64 + ht * 16 + n15] ? 0.0f : 1.0f;
        bn[ht] = bc[ht];
        mn[ht] = mc[ht];
    }

#pragma unroll 1
    for (int hws = 0; hws < 16; ++hws) {
        if (hws < 15) {
#pragma unroll
            for (int ht = 0; ht < 4; ++ht) {
                int tg = (hws + 1) * 16 + w * 4 + ht;
                bn[ht] = *reinterpret_cast<const bf16x8_t*>(kpf + KPF_IDX(b, tg, n, kg) + n15 * 8);
                mn[ht] = mask[b * HWN + (hws + 1) * 256 + w * 64 + ht * 16 + n15] ? 0.0f : 1.0f;
            }
        }
#pragma unroll
        for (int ht = 0; ht < 4; ++ht) {
            f32x4_t acc = {0.f, 0.f, 0.f, 0.f};
            acc = __builtin_amdgcn_mfma_f32_16x16x32_bf16(ahi, bc[ht], acc, 0, 0, 0);
            acc = __builtin_amdgcn_mfma_f32_16x16x32_bf16(alo, bc[ht], acc, 0, 0, 0);
#pragma unroll
            for (int r = 0; r < 4; ++r)
                lt[kg * 4 + r][w * 64 + ht * 16 + n15] = __expf(acc[r]) * mc[ht] * invq[r];
        }
        __syncthreads();
        // cooperative store: wave w emits rows w*4..w*4+3, 1KB contiguous each
#pragma unroll
        for (int j = 0; j < 4; ++j) {
            int row = w * 4 + j;
            int qrow = qt * 16 + row;
            f32x4_t v4 = *(const f32x4_t*)&lt[row][lane * 4];
            if (qrow < QQ)
                __builtin_nontemporal_store(v4,
                    (f32x4_t*)(out + (((size_t)(b * QQ + qrow)) * NH + n) * HWN + hws * 256 + lane * 4));
        }
        __syncthreads();
#pragma unroll
        for (int ht = 0; ht < 4; ++ht) { bc[ht] = bn[ht]; mc[ht] = mn[ht]; }
    }
}

extern "C" void kernel_launch(void* const* d_in, const int* in_sizes, int n_in,
                              void* d_out, int out_size, void* d_ws, size_t ws_size,
                              hipStream_t stream) {
    const float* q    = (const float*)d_in[0];
    const float* k    = (const float*)d_in[1];
    const float* Wq   = (const float*)d_in[2];
    const float* bq   = (const float*)d_in[3];
    const float* Wk   = (const float*)d_in[4];
    const float* bk   = (const float*)d_in[5];
    const int*   mask = (const int*)d_in[6];
    float* out = (float*)d_out;

    char* base = (char*)d_ws;
    unsigned short* kpf  = (unsigned short*)(base);              // 33,554,432 B
    unsigned short* qphi = (unsigned short*)(base + 33554432);   //    917,504 B
    unsigned short* qplo = (unsigned short*)(base + 34471936);   //    917,504 B
    float*  WqT     = (float*)(base + 35389440);                 //    262,144 B
    unsigned short* Wkbf = (unsigned short*)(base + 35651584);   //    131,072 B
    float*  partial = (float*)(base + 35782656);                 //  1,835,008 B
    float*  inv     = (float*)(base + 37617664);                 //      6,400 B
    if (ws_size < (size_t)37624064) return;

    k_prep  <<<dim3(512), dim3(256), 0, stream>>>(Wq, Wk, WqT, Wkbf);
    k_qproj <<<dim3(448), dim3(256), 0, stream>>>(q, WqT, bq, qphi, qplo);
    k_kproj4<<<dim3(64, 16), dim3(512), 0, stream>>>(k, Wkbf, bk, kpf);
    k_sums  <<<dim3(64, 16), dim3(256), 0, stream>>>(qphi, qplo, kpf, mask, partial);
    k_invsum<<<dim3(1600), dim3(256), 0, stream>>>(partial, inv);
    k_write <<<dim3(7, 8, 16), dim3(256), 0, stream>>>(qphi, qplo, kpf, mask, inv, out);
}